// Round 8
// baseline (101.062 us; speedup 1.0000x reference)
//
#include <hip/hip_runtime.h>
#include <stdint.h>

// RadialAEVComputer: out[b,i,s*16+p] = sum_{j: 0<d<RC, spc(j)=s} exp(-16(d-shf_p)^2)*fc(d)
// B=64, N=256, S=4, P=16, RC=5.2, shf_p = 0.9 + 0.26875*p
// d_in[0]: fp32 [B,256,256]; d_in[1]: int32 [B,256] (1..4); d_out: fp32 [B,256,64]
//
// Block = 256 threads = 4 waves, one 16-row tile. Grid = B*16 = 1024.
// Phase B: each wave compacts 4 rows: float4 loads (j=4*lane+e), validity+fc,
//          ballot-rank compaction of (d, fc) into LDS, species-major.
// Phase C: thread = (row ti, shift p); 4 species segments, each a tight
//          ds_read_b64 -> exp2 -> fma loop. No selects, no invalid work.

static __device__ __forceinline__ int mbcnt64(uint64_t m) {
    // popcount(m & lanemask_lt)
    int lo = __builtin_amdgcn_mbcnt_lo((uint32_t)m, 0u);
    return __builtin_amdgcn_mbcnt_hi((uint32_t)(m >> 32), lo);
}

__global__ __launch_bounds__(256) void aev_kernel(
    const float* __restrict__ dmat,      // fp32 [B,256,256]
    const int* __restrict__ species,     // int32 [B,256], values 1..4
    float* __restrict__ out)             // fp32 [B,256,64]
{
    __shared__ int    rbase[16][5];      // per-row species prefix offsets
    __shared__ float2 comp[16][258];     // per-row compacted (d, fc), species-major

    const int tid  = threadIdx.x;
    const int w    = tid >> 6;
    const int lane = tid & 63;
    const int blk  = (int)blockIdx.x;    // 16-row tile index; global row = blk*16 + r
    const int b    = blk >> 4;

    // species of this lane's 4 neighbors (j = 4*lane+e) — row-independent
    const int4 s4 = ((const int4*)(species + (b << 8)))[lane];
    const int sv[4] = {s4.x - 1, s4.y - 1, s4.z - 1, s4.w - 1};   // 0..3

    // ---- Phase B: each wave compacts 4 rows ----
    for (int rr = 0; rr < 4; ++rr) {
        const int r = (w << 2) + rr;
        const float4* rp = (const float4*)(dmat + ((size_t)(blk * 16 + r) << 8));
        float4 q4 = rp[lane];
        float d[4] = {q4.x, q4.y, q4.z, q4.w};

        float dc[4], fw[4]; bool valid[4];
        #pragma unroll
        for (int e = 0; e < 4; ++e) {
            bool v = (d[e] < 5.2f) && (d[e] != 0.0f);   // false for NaN
            float x = v ? d[e] : 2.6f;                  // keep cos arg in-domain
            // fc = 0.5*cos(pi*d/RC)+0.5 ; v_cos takes revolutions: x/(2*RC)
            float fc = 0.5f * __builtin_amdgcn_cosf(x * (0.5f / 5.2f)) + 0.5f;
            valid[e] = v; dc[e] = x; fw[e] = fc;
        }

        // per-(element, species) lane masks: 3 ballots per element
        uint64_t bal[4][4];
        #pragma unroll
        for (int e = 0; e < 4; ++e) {
            uint64_t bv = __ballot(valid[e]);
            uint64_t b0 = __ballot((sv[e] & 1) != 0);
            uint64_t b1 = __ballot((sv[e] & 2) != 0);
            bal[e][0] = bv & ~b0 & ~b1;
            bal[e][1] = bv &  b0 & ~b1;
            bal[e][2] = bv & ~b0 &  b1;
            bal[e][3] = bv &  b0 &  b1;
        }

        // species totals -> exclusive prefix
        int sb[5];
        sb[0] = 0;
        #pragma unroll
        for (int s = 0; s < 4; ++s)
            sb[s + 1] = sb[s] + __popcll(bal[0][s]) + __popcll(bal[1][s])
                               + __popcll(bal[2][s]) + __popcll(bal[3][s]);

        int run[4];
        #pragma unroll
        for (int s = 0; s < 4; ++s) run[s] = sb[s];

        // rank + scatter, element by element
        #pragma unroll
        for (int e = 0; e < 4; ++e) {
            const int s = sv[e];
            uint64_t m = bal[e][0];
            m = (s == 1) ? bal[e][1] : m;
            m = (s == 2) ? bal[e][2] : m;
            m = (s == 3) ? bal[e][3] : m;
            int base = run[0];
            base = (s == 1) ? run[1] : base;
            base = (s == 2) ? run[2] : base;
            base = (s == 3) ? run[3] : base;
            int slot = base + mbcnt64(m);
            slot = (slot < 257) ? slot : 257;           // OOB insurance
            if (valid[e]) comp[r][slot] = make_float2(dc[e], fw[e]);
            #pragma unroll
            for (int s2 = 0; s2 < 4; ++s2) run[s2] += __popcll(bal[e][s2]);
        }

        if (lane == 0) {
            #pragma unroll
            for (int s = 0; s <= 4; ++s) rbase[r][s] = sb[s];
        }
    }
    __syncthreads();

    // ---- Phase C: thread = (row ti, shift p) ----
    const int ti = tid >> 4;
    const int p  = tid & 15;
    const float shfp = 0.9f + 0.26875f * (float)p;
    const size_t ob = (((size_t)blk * 16 + (size_t)ti) << 6) + (size_t)p;

    #pragma unroll
    for (int s = 0; s < 4; ++s) {
        const int beg = rbase[ti][s];
        const int end = rbase[ti][s + 1];
        float acc = 0.0f;
        for (int k = beg; k < end; ++k) {
            float2 dw = comp[ti][k];                    // 16-lane broadcast read
            float u = dw.x - shfp;
            // exp(-16*u^2) = exp2(u^2 * -16*log2(e)); arg <= 0, all finite
            float t = __builtin_amdgcn_exp2f(u * u * -23.083120654223414f);
            acc = __builtin_fmaf(t, dw.y, acc);
        }
        out[ob + ((size_t)s << 4)] = acc;
    }
}

extern "C" void kernel_launch(void* const* d_in, const int* in_sizes, int n_in,
                              void* d_out, int out_size, void* d_ws, size_t ws_size,
                              hipStream_t stream) {
    const float* dmat  = (const float*)d_in[0];          // fp32 [B,256,256]
    const int* species = (const int*)d_in[1];            // int32 [B,256]
    float* o           = (float*)d_out;                  // fp32 [B,256,64]
    const int B = in_sizes[1] >> 8;                      // N = 256
    aev_kernel<<<dim3(B * 16), 256, 0, stream>>>(dmat, species, o);
}

// Round 9
// 79.132 us; speedup vs baseline: 1.2771x; 1.2771x over previous
//
#include <hip/hip_runtime.h>
#include <stdint.h>

// RadialAEVComputer: out[b,i,s*16+p] = sum_{j: 0<d<RC, spc(j)=s} exp(-16(d-shf_p)^2)*fc(d)
// B=64, N=256, S=4, P=16, RC=5.2, shf_p = 0.9 + 0.26875*p
// d_in[0]: fp32 [B,256,256]; d_in[1]: int32 [B,256] (1..4); d_out: fp32 [B,256,64]
//
// Block = 256 = 4 waves, ONE ROW PER WAVE (grid = B*64 = 4096).
// Phase A: per-b species permutation pos[j] (2 ballots; exact bijection, no
//          validity gating). Same for all rows of b; recomputed per block (cheap).
// Phase B: stage row permuted: comp[w][pos[j]] = (d_clamped, fc*mask).
// Phase C: lane=(p,q): 4 wave-uniform species segments, stride-4 over quad q;
//          no selects, no divergence beyond a 1-iter tail. Quad shfl-reduce,
//          one coalesced 256B nontemporal wave store.

static __device__ __forceinline__ int mbcnt64(uint64_t m) {
    // popcount(m & lanemask_lt)
    int lo = __builtin_amdgcn_mbcnt_lo((uint32_t)m, 0u);
    return __builtin_amdgcn_mbcnt_hi((uint32_t)(m >> 32), lo);
}

__global__ __launch_bounds__(256) void aev_kernel(
    const float* __restrict__ dmat,      // fp32 [B,256,256]
    const int* __restrict__ species,     // int32 [B,256], values 1..4
    float* __restrict__ out)             // fp32 [B,256,64]
{
    __shared__ alignas(16) int pos[256]; // species-major permutation of j (per b)
    __shared__ float2 comp[4][260];      // per-wave permuted (d, fc*mask)
    __shared__ int    cntm[4][4];        // per-wave per-species counts

    const int tid  = threadIdx.x;
    const int w    = tid >> 6;
    const int lane = tid & 63;
    const int blk  = (int)blockIdx.x;
    const int row  = blk * 4 + w;        // global row = b*256 + i
    const int b    = blk >> 6;

    // ---- issue the global row load ASAP (consumed in phase B) ----
    const float4* rp = (const float4*)(dmat + ((size_t)row << 8));
    const float4 q4 = rp[lane];          // j = 4*lane .. 4*lane+3

    // ---- phase A: per-b species permutation ----
    int sj = species[(b << 8) + tid] - 1;           // 0..3
    sj = (sj < 0) ? 0 : ((sj > 3) ? 3 : sj);        // insurance only
    const uint64_t bs0 = __ballot((sj & 1) != 0);
    const uint64_t bs1 = __ballot((sj & 2) != 0);
    const uint64_t m0 = ~bs0 & ~bs1, m1 = bs0 & ~bs1;
    const uint64_t m2 = ~bs0 &  bs1, m3 = bs0 &  bs1;
    if (lane == 0) {
        cntm[w][0] = __popcll(m0); cntm[w][1] = __popcll(m1);
        cntm[w][2] = __popcll(m2); cntm[w][3] = __popcll(m3);
    }
    uint64_t msel = m0;
    msel = (sj == 1) ? m1 : msel;
    msel = (sj == 2) ? m2 : msel;
    msel = (sj == 3) ? m3 : msel;
    const int rank = mbcnt64(msel);
    __syncthreads();

    // segment bases (wave-uniform registers) + this thread's permuted slot
    int seg[5];
    seg[0] = 0;
    int base = 0;
    #pragma unroll
    for (int s = 0; s < 4; ++s) {
        const int t4 = cntm[0][s] + cntm[1][s] + cntm[2][s] + cntm[3][s];
        base += (s < sj) ? t4 : 0;
        seg[s + 1] = seg[s] + t4;
    }
    #pragma unroll
    for (int w2 = 0; w2 < 3; ++w2) base += (w2 < w) ? cntm[w2][sj] : 0;
    pos[tid] = base + rank;              // exact bijection [0,256)
    __syncthreads();

    // ---- phase B: stage this wave's row, permuted ----
    {
        const int4 p4 = *(const int4*)&pos[4 * lane];
        const float dv[4] = {q4.x, q4.y, q4.z, q4.w};
        const int   pp[4] = {p4.x, p4.y, p4.z, p4.w};
        #pragma unroll
        for (int e = 0; e < 4; ++e) {
            const float dd = dv[e];
            const bool  v  = (dd < 5.2f) && (dd != 0.0f);   // false for NaN
            const float x  = v ? dd : 2.6f;                 // cos arg in-domain
            // fc = 0.5*cos(pi*d/RC)+0.5 ; v_cos takes revolutions: x/(2*RC)
            const float fc = 0.5f * __builtin_amdgcn_cosf(x * (0.5f / 5.2f)) + 0.5f;
            comp[w][pp[e]] = make_float2(x, v ? fc : 0.0f);
        }
    }
    __syncthreads();

    // ---- phase C: lane = (p = shift, q = quad slot) ----
    const int p = lane >> 2;             // 0..15
    const int q = lane & 3;              // 0..3
    const float shfp = 0.9f + 0.26875f * (float)p;
    float accs[4];
    #pragma unroll
    for (int s = 0; s < 4; ++s) {
        float a = 0.0f;
        for (int k = seg[s] + q; k < seg[s + 1]; k += 4) {
            const float2 dw = comp[w][k];        // quad reads 32B; 16-way broadcast
            const float u = dw.x - shfp;
            // exp(-16*u^2) = exp2(u^2 * -16*log2(e)); arg in [-577, 0]
            const float t = __builtin_amdgcn_exp2f(u * u * -23.083120654223414f);
            a = __builtin_fmaf(t, dw.y, a);
        }
        accs[s] = a;
    }
    // quad reduce (lanes 4p..4p+3 share p)
    #pragma unroll
    for (int s = 0; s < 4; ++s) {
        accs[s] += __shfl_xor(accs[s], 1, 64);
        accs[s] += __shfl_xor(accs[s], 2, 64);
    }
    // lane (p,q) stores species s=q -> one coalesced 256B wave store
    float vout = accs[0];
    vout = (q == 1) ? accs[1] : vout;
    vout = (q == 2) ? accs[2] : vout;
    vout = (q == 3) ? accs[3] : vout;
    __builtin_nontemporal_store(vout, &out[((size_t)row << 6) + (size_t)((q << 4) + p)]);
}

extern "C" void kernel_launch(void* const* d_in, const int* in_sizes, int n_in,
                              void* d_out, int out_size, void* d_ws, size_t ws_size,
                              hipStream_t stream) {
    const float* dmat  = (const float*)d_in[0];          // fp32 [B,256,256]
    const int* species = (const int*)d_in[1];            // int32 [B,256]
    float* o           = (float*)d_out;                  // fp32 [B,256,64]
    const int B = in_sizes[1] >> 8;                      // N = 256
    aev_kernel<<<dim3(B * 64), 256, 0, stream>>>(dmat, species, o);
}